// Round 7
// baseline (145.470 us; speedup 1.0000x reference)
//
#include <hip/hip_runtime.h>

namespace {
constexpr int Bc  = 4;
constexpr int Lc  = 4096;
constexpr int Dc  = 2048;
constexpr int Gc  = 32;
constexpr int GSc = 64;
constexpr int CT  = 256;                 // timesteps per chunk
constexpr int NC  = Lc / CT;             // 16 chunks per bg column
constexpr int JB  = NC / 2;              // 8 blocks per bg (2 chunks each)
constexpr float EPSc = 1e-5f;
constexpr long long NY = (long long)Bc * Lc * Dc;   // 33,554,432
typedef float vfloat4 __attribute__((ext_vector_type(4)));
#define SCOPE_AGENT __HIP_MEMORY_SCOPE_AGENT
}

// Zero the publish flags every launch (ws not re-poisoned between replays).
__global__ void kInit(int* __restrict__ flags) {
    int t = blockIdx.x * blockDim.x + threadIdx.x;
    if (t < Bc * Gc * NC) flags[t] = 0;
}

// Single-pass timestep-norm with decoupled lookback.
// Grid = 1024 blocks = exact residency capacity at 4 blocks/CU (128 VGPR,
// 8.5 KB LDS) -> all blocks co-resident, publish-before-wait -> deadlock-free.
// Block (bg, j) owns chunks j and j+JB. x is read from HBM exactly once and
// held in 64 VGPRs from load to normalize.
__global__ __launch_bounds__(256, 4) void kMain(
        const float* __restrict__ x,
        const int* __restrict__ prev_count,
        const float* __restrict__ prev_mean,
        const float* __restrict__ prev_var,
        const int* __restrict__ mask,
        const float* __restrict__ w,
        const float* __restrict__ bias,
        float* __restrict__ y,
        float* __restrict__ out_count,
        float* __restrict__ out_mean,
        float* __restrict__ out_var,
        int* __restrict__ flags,
        double* __restrict__ part) {
    const int blk = blockIdx.x;
    const int bg = blk >> 3, j = blk & 7;
    const int b = bg >> 5, g = bg & (Gc - 1);
    const int tid = threadIdx.x;
    const int r16 = tid >> 4, col4 = tid & 15;

    __shared__ float  sm[CT];
    __shared__ float  smean[CT], srstd[CT];
    __shared__ double s1[256], s2[256];
    __shared__ int    scnt[256];
    __shared__ double cLDS[3];

    const double c0    = (double)prev_count[b];
    const double mean0 = (double)prev_mean[bg];
    const double M2_0  = (double)prev_var[bg] * fmax(c0, 1.0);
    const float c0f = (float)c0, mean0f = (float)mean0, M2_0f = (float)M2_0;

    const float4 wv  = *reinterpret_cast<const float4*>(w + g * GSc + col4 * 4);
    const float4 bvv = *reinterpret_cast<const float4*>(bias + g * GSc + col4 * 4);

    #pragma unroll
    for (int phase = 0; phase < 2; ++phase) {
        const int c = j + phase * JB;
        const int tbase = c * CT;
        const long long xbase = ((long long)b * Lc + tbase) * Dc + (long long)g * GSc + col4 * 4;

        // ---- load chunk into registers (the ONLY HBM read of x) ----
        float4 xa[16];
        #pragma unroll
        for (int it = 0; it < 16; ++it) {
            xa[it] = *reinterpret_cast<const float4*>(x + xbase + (long long)(it * 16 + r16) * Dc);
        }

        // ---- per-timestep group means (16-lane segmented shfl) ----
        #pragma unroll
        for (int it = 0; it < 16; ++it) {
            float s = xa[it].x + xa[it].y + xa[it].z + xa[it].w;
            s += __shfl_xor(s, 1);
            s += __shfl_xor(s, 2);
            s += __shfl_xor(s, 4);
            s += __shfl_xor(s, 8);
            if (col4 == 0) sm[it * 16 + r16] = s * (1.0f / GSc);
        }
        __syncthreads();

        // ---- masked fp64 inclusive scan, 1 timestep per thread ----
        const float v = sm[tid];
        const int q = mask[(long long)b * Lc + tbase + tid];
        double l1 = 0.0, l2 = 0.0; int lc = 0;
        if (q) { l1 = v; l2 = (double)v * v; lc = 1; }
        s1[tid] = l1; s2[tid] = l2; scnt[tid] = lc;
        __syncthreads();
        for (int off = 1; off < 256; off <<= 1) {
            double a1 = 0.0, a2 = 0.0; int ac = 0;
            if (tid >= off) { a1 = s1[tid - off]; a2 = s2[tid - off]; ac = scnt[tid - off]; }
            __syncthreads();
            s1[tid] += a1; s2[tid] += a2; scnt[tid] += ac;
            __syncthreads();
        }
        const double inc1 = s1[tid], inc2 = s2[tid];
        const int incc = scnt[tid];

        // ---- publish this chunk's totals (BEFORE any wait -> acyclic) ----
        if (tid == 255) {
            double* p = part + (long long)(bg * NC + c) * 3;
            __hip_atomic_store(&p[0], inc1, __ATOMIC_RELAXED, SCOPE_AGENT);
            __hip_atomic_store(&p[1], inc2, __ATOMIC_RELAXED, SCOPE_AGENT);
            __hip_atomic_store(&p[2], (double)incc, __ATOMIC_RELAXED, SCOPE_AGENT);
            __hip_atomic_store(&flags[bg * NC + c], 1, __ATOMIC_RELEASE, SCOPE_AGENT);
        }

        // ---- parallel lookback: lane l of wave 0 polls predecessor l ----
        if (tid < 64) {
            double a1 = 0.0, a2 = 0.0, ac = 0.0;
            if (tid < c) {
                const int fi = bg * NC + tid;
                while (__hip_atomic_load(&flags[fi], __ATOMIC_ACQUIRE, SCOPE_AGENT) == 0) {
                    __builtin_amdgcn_s_sleep(1);
                }
                const double* p = part + (long long)fi * 3;
                a1 = __hip_atomic_load(&p[0], __ATOMIC_RELAXED, SCOPE_AGENT);
                a2 = __hip_atomic_load(&p[1], __ATOMIC_RELAXED, SCOPE_AGENT);
                ac = __hip_atomic_load(&p[2], __ATOMIC_RELAXED, SCOPE_AGENT);
            }
            #pragma unroll
            for (int o = 1; o < 16; o <<= 1) {
                a1 += __shfl_xor(a1, o);
                a2 += __shfl_xor(a2, o);
                ac += __shfl_xor(ac, o);
            }
            if (tid == 0) { cLDS[0] = a1; cLDS[1] = a2; cLDS[2] = ac; }
        }
        __syncthreads();

        // ---- finalize this timestep (fp32 rcp/rsq) ----
        const double run1 = cLDS[0] + inc1;
        const double run2 = cLDS[1] + inc2;
        const double runc = cLDS[2] + (double)incc;
        {
            float run1f = (float)run1, run2f = (float)run2, cv = (float)runc;
            float ctot = c0f + cv, csafe = fmaxf(ctot, 1.0f);
            float invcs = __builtin_amdgcn_rcpf(csafe);
            float meanT = fmaf(c0f, mean0f, run1f) * invcs;
            float M2 = M2_0f;
            if (runc > 0.0) {
                float invcv = __builtin_amdgcn_rcpf(cv);
                M2 += run2f - run1f * run1f * invcv;
                float dd = run1f * invcv - mean0f;
                M2 += dd * dd * c0f * cv * invcs;
            }
            float varT = M2 * invcs;
            smean[tid] = meanT;
            srstd[tid] = __builtin_amdgcn_rsqf(varT + EPSc);
        }

        // ---- final-state outputs from the last timestep (fp64) ----
        if (c == NC - 1 && tid == 255) {
            double ctot = c0 + runc, csafe = fmax(ctot, 1.0);
            double meanF = (c0 * mean0 + run1) / csafe;
            double M2 = M2_0;
            if (runc > 0.0) {
                M2 += run2 - run1 * run1 / runc;
                double dd = run1 / runc - mean0;
                M2 += dd * dd * c0 * runc / csafe;
            }
            if (g == 0) out_count[b] = (float)ctot;   // read back as float32
            out_mean[bg] = (float)meanF;
            out_var[bg]  = (float)(M2 / csafe);
        }
        __syncthreads();

        // ---- normalize from registers, NT store ----
        #pragma unroll
        for (int it = 0; it < 16; ++it) {
            const int r = it * 16 + r16;
            const float mean = smean[r];
            const float rstd = srstd[r];
            vfloat4 yv;
            yv.x = (xa[it].x - mean) * rstd * wv.x + bvv.x;
            yv.y = (xa[it].y - mean) * rstd * wv.y + bvv.y;
            yv.z = (xa[it].z - mean) * rstd * wv.z + bvv.z;
            yv.w = (xa[it].w - mean) * rstd * wv.w + bvv.w;
            __builtin_nontemporal_store(
                yv, reinterpret_cast<vfloat4*>(y + xbase + (long long)(it * 16 + r16) * Dc));
        }
        __syncthreads();   // protect sm/smean/s1/s2 reuse in next phase
    }
}

extern "C" void kernel_launch(void* const* d_in, const int* in_sizes, int n_in,
                              void* d_out, int out_size, void* d_ws, size_t ws_size,
                              hipStream_t stream) {
    const float* x         = (const float*)d_in[0];
    const int* prev_count  = (const int*)d_in[1];
    const float* prev_mean = (const float*)d_in[2];
    const float* prev_var  = (const float*)d_in[3];
    const int* mask        = (const int*)d_in[4];   // bool -> int32 per harness
    const float* weight    = (const float*)d_in[5];
    const float* bias      = (const float*)d_in[6];

    float* out       = (float*)d_out;
    float* y         = out;
    float* out_count = out + NY;
    float* out_mean  = out_count + Bc;
    float* out_var   = out_mean + (long long)Bc * Gc;

    double* part = (double*)d_ws;                                  // 128*16*3 doubles = 48 KB
    int* flags   = (int*)((char*)d_ws + (size_t)Bc * Gc * NC * 3 * sizeof(double));

    kInit<<<(Bc * Gc * NC + 255) / 256, 256, 0, stream>>>(flags);
    kMain<<<Bc * Gc * JB, 256, 0, stream>>>(x, prev_count, prev_mean, prev_var,
                                            mask, weight, bias, y,
                                            out_count, out_mean, out_var, flags, part);
}